// Round 4
// baseline (1266.061 us; speedup 1.0000x reference)
//
#include <hip/hip_runtime.h>

// ---------- types ----------
typedef __attribute__((ext_vector_type(8))) short bf16x8;
typedef __attribute__((ext_vector_type(4))) float f32x4;

__device__ __forceinline__ unsigned short f2bf(float f) {
  union { float f; unsigned u; } v; v.f = f;
  unsigned r = v.u + 0x7FFFu + ((v.u >> 16) & 1u);
  return (unsigned short)(r >> 16);
}
__device__ __forceinline__ float bf2f(unsigned short s) {
  union { unsigned u; float f; } v; v.u = ((unsigned)s) << 16;
  return v.f;
}

// Problem constants
// B=64 T=512 E=300 V=50000 H=2048 WP=2 OUT=5
// padded: EP=320, TP=516, KP=1600, M=B*T=32768

// ---------- kernel 1: W1 -> W1bT bf16 [2048][1600] (transposed, K-padded) ----------
__global__ __launch_bounds__(256) void prepw1_kernel(
    const float* __restrict__ W1, unsigned short* __restrict__ W1bT) {
  __shared__ float tile[64][65];
  int kb = blockIdx.x % 25;   // K tile (padded K = 1600 = 25*64)
  int hb = blockIdx.x / 25;   // H tile (2048 = 32*64)
  int win = kb / 5;
  int e0 = (kb % 5) << 6;
  int hh = threadIdx.x & 63;
  int kq = threadIdx.x >> 6;
#pragma unroll
  for (int kk = kq; kk < 64; kk += 4) {
    int e = e0 + kk;
    float v = 0.f;
    if (e < 300) v = W1[(size_t)(win * 300 + e) * 2048 + hb * 64 + hh];
    tile[kk][hh] = v;
  }
  __syncthreads();
  int kk = threadIdx.x & 63;
  int hq = threadIdx.x >> 6;
#pragma unroll
  for (int h = hq; h < 64; h += 4) {
    W1bT[(size_t)(hb * 64 + h) * 1600 + kb * 64 + kk] = f2bf(tile[kk][h]);
  }
}

// ---------- kernel 2: gather embeddings -> P bf16 [64][516][320] ----------
__global__ __launch_bounds__(320) void gather_kernel(
    const int* __restrict__ idxs, const float* __restrict__ emb,
    unsigned short* __restrict__ P) {
  int g = blockIdx.x;   // b*516 + tp
  int b = g / 516;
  int tp = g - b * 516;
  int tok = 0;
  if (tp >= 2 && tp < 514) tok = idxs[b * 512 + tp - 2];
  int e = threadIdx.x;
  float v = (e < 300) ? emb[(size_t)tok * 300 + e] : 0.f;
  P[(size_t)g * 320 + e] = f2bf(v);
}

// ---------- kernel 3: GEMM  Z[b*512+t][h] = sum_k A * W1bT  (bf16 in, bf16 out, f32 acc) ----------
// A[r=(b,t)][k=(win,e)] read directly from P at ((b*516 + t + win)*320 + e)
__global__ __launch_bounds__(256) void gemm_kernel(
    const unsigned short* __restrict__ P,
    const unsigned short* __restrict__ W1bT,
    unsigned short* __restrict__ Z) {
  __shared__ unsigned short As[128 * 64];  // [row][k] 16KB
  __shared__ unsigned short Bs[128 * 64];  // [col][k] 16KB
  const int tid = threadIdx.x;
  const int lane = tid & 63;
  const int w = tid >> 6;
  const int wm = w >> 1, wn = w & 1;
  const int lr = lane & 15;
  const int lk = (lane >> 4) << 3;

  const int nt = blockIdx.x & 15;   // 2048/128
  const int mt = blockIdx.x >> 4;   // 32768/128
  const int b = mt >> 2;            // 512/128 = 4 tiles per batch
  const int t0 = (mt & 3) << 7;

  f32x4 acc[4][4];
#pragma unroll
  for (int i = 0; i < 4; i++)
#pragma unroll
    for (int j = 0; j < 4; j++) acc[i][j] = (f32x4){0.f, 0.f, 0.f, 0.f};

  for (int kt = 0; kt < 25; ++kt) {
    const int win = kt / 5;
    const int e0 = (kt % 5) << 6;
    // stage A: 1024 chunks of 16B
#pragma unroll
    for (int j = 0; j < 4; ++j) {
      int chunk = tid + j * 256;
      int row = chunk >> 3, kb = chunk & 7;
      const unsigned short* src =
          P + (size_t)(b * 516 + t0 + row + win) * 320 + e0 + (kb << 3);
      __builtin_amdgcn_global_load_lds(
          (const __attribute__((address_space(1))) unsigned int*)src,
          (__attribute__((address_space(3))) unsigned int*)&As[chunk << 3],
          16, 0, 0);
    }
    // stage B
#pragma unroll
    for (int j = 0; j < 4; ++j) {
      int chunk = tid + j * 256;
      int col = chunk >> 3, kb = chunk & 7;
      const unsigned short* src =
          W1bT + (size_t)(nt * 128 + col) * 1600 + (kt << 6) + (kb << 3);
      __builtin_amdgcn_global_load_lds(
          (const __attribute__((address_space(1))) unsigned int*)src,
          (__attribute__((address_space(3))) unsigned int*)&Bs[chunk << 3],
          16, 0, 0);
    }
    __syncthreads();
#pragma unroll
    for (int ks = 0; ks < 64; ks += 32) {
      bf16x8 af[4], bv[4];
#pragma unroll
      for (int am = 0; am < 4; ++am)
        af[am] = *(const bf16x8*)&As[((wm << 6) + (am << 4) + lr) * 64 + ks + lk];
#pragma unroll
      for (int bn = 0; bn < 4; ++bn)
        bv[bn] = *(const bf16x8*)&Bs[((wn << 6) + (bn << 4) + lr) * 64 + ks + lk];
#pragma unroll
      for (int am = 0; am < 4; ++am)
#pragma unroll
        for (int bn = 0; bn < 4; ++bn)
          acc[am][bn] = __builtin_amdgcn_mfma_f32_16x16x32_bf16(
              af[am], bv[bn], acc[am][bn], 0, 0, 0);
    }
    __syncthreads();
  }

  const int rbase = mt * 128 + (wm << 6) + ((lane >> 4) << 2);
  const int cbase = nt * 128 + (wn << 6) + lr;
#pragma unroll
  for (int am = 0; am < 4; ++am)
#pragma unroll
    for (int bn = 0; bn < 4; ++bn)
#pragma unroll
      for (int j = 0; j < 4; ++j) {
        int r = rbase + (am << 4) + j;
        int c = cbase + (bn << 4);
        Z[(size_t)r * 2048 + c] = f2bf(acc[am][bn][j]);
      }
}

// ---------- kernel 4: sequential scan, one block per batch ----------
__global__ __launch_bounds__(1024) void scan_kernel(
    const unsigned short* __restrict__ Z, const float* __restrict__ W1,
    const float* __restrict__ b1, const float* __restrict__ W2,
    const float* __restrict__ b2, const float* __restrict__ istate,
    float* __restrict__ out) {
  const int b = blockIdx.x;
  const int tid = threadIdx.x;
  const int lane = tid & 63;
  const int wid = tid >> 6;
  const unsigned short* Zb = Z + (size_t)b * 512 * 2048;
  float* outb = out + (size_t)b * 512 * 5;

  float w1p0[10], w1p1[10], w20[5], w21[5];
#pragma unroll
  for (int j = 0; j < 10; ++j) {
    w1p0[j] = W1[(size_t)(1500 + j) * 2048 + tid];
    w1p1[j] = W1[(size_t)(1500 + j) * 2048 + tid + 1024];
  }
#pragma unroll
  for (int k = 0; k < 5; ++k) {
    w20[k] = W2[tid * 5 + k];
    w21[k] = W2[(tid + 1024) * 5 + k];
  }
  float bias0 = b1[tid], bias1 = b1[tid + 1024];

  __shared__ float prevS[10];
  __shared__ float ypart[16][5];
  __shared__ float yfin[5];
  if (tid < 10) prevS[tid] = istate[tid];
  __syncthreads();

  float z0 = bf2f(Zb[tid]);
  float z1 = bf2f(Zb[tid + 1024]);

  for (int t = 0; t < 512; ++t) {
    float x0 = z0 + bias0, x1 = z1 + bias1;
#pragma unroll
    for (int j = 0; j < 10; ++j) {
      float pj = prevS[j];
      x0 = fmaf(pj, w1p0[j], x0);
      x1 = fmaf(pj, w1p1[j], x1);
    }
    x0 = fmaxf(x0, 0.f);
    x1 = fmaxf(x1, 0.f);
    float y[5];
#pragma unroll
    for (int k = 0; k < 5; ++k) y[k] = x0 * w20[k] + x1 * w21[k];
    if (t + 1 < 512) {  // prefetch next Z slice; latency hides under reduction
      z0 = bf2f(Zb[(size_t)(t + 1) * 2048 + tid]);
      z1 = bf2f(Zb[(size_t)(t + 1) * 2048 + tid + 1024]);
    }
#pragma unroll
    for (int k = 0; k < 5; ++k)
#pragma unroll
      for (int off = 32; off > 0; off >>= 1) y[k] += __shfl_xor(y[k], off, 64);
    if (lane == 0) {
#pragma unroll
      for (int k = 0; k < 5; ++k) ypart[wid][k] = y[k];
    }
    __syncthreads();
    if (tid < 5) {
      float s = b2[tid];
#pragma unroll
      for (int ww = 0; ww < 16; ++ww) s += ypart[ww][tid];
      outb[t * 5 + tid] = s;
      yfin[tid] = s;
    }
    __syncthreads();
    if (tid < 5) {
      float m = fmaxf(fmaxf(fmaxf(yfin[0], yfin[1]), fmaxf(yfin[2], yfin[3])),
                      yfin[4]);
      float d = 0.f;
#pragma unroll
      for (int k = 0; k < 5; ++k) d += expf(yfin[k] - m);
      float p = expf(yfin[tid] - m) / d;
      float carry = prevS[tid + 5];  // read before overwrite (lockstep wave)
      prevS[tid] = carry;
      prevS[tid + 5] = p;
    }
    __syncthreads();
  }
}

// ---------- launcher ----------
extern "C" void kernel_launch(void* const* d_in, const int* in_sizes, int n_in,
                              void* d_out, int out_size, void* d_ws,
                              size_t ws_size, hipStream_t stream) {
  const int* idxs = (const int*)d_in[0];
  const float* emb = (const float*)d_in[1];
  const float* W1 = (const float*)d_in[2];
  const float* b1 = (const float*)d_in[3];
  const float* W2 = (const float*)d_in[4];
  const float* b2 = (const float*)d_in[5];
  const float* istate = (const float*)d_in[6];
  float* out = (float*)d_out;

  char* ws = (char*)d_ws;
  unsigned short* P = (unsigned short*)ws;                          // 21,135,360 B
  unsigned short* W1bT = (unsigned short*)(ws + 21135360);          // 6,553,600 B
  unsigned short* Z = (unsigned short*)(ws + 21135360 + 6553600);   // 134,217,728 B

  hipLaunchKernelGGL(prepw1_kernel, dim3(25 * 32), dim3(256), 0, stream, W1, W1bT);
  hipLaunchKernelGGL(gather_kernel, dim3(64 * 516), dim3(320), 0, stream, idxs, emb, P);
  hipLaunchKernelGGL(gemm_kernel, dim3(256 * 16), dim3(256), 0, stream, P, W1bT, Z);
  hipLaunchKernelGGL(scan_kernel, dim3(64), dim3(1024), 0, stream, Z, W1, b1, W2, b2,
                     istate, out);
}

// Round 5
// 818.838 us; speedup vs baseline: 1.5462x; 1.5462x over previous
//
#include <hip/hip_runtime.h>

// ---------- types ----------
typedef __attribute__((ext_vector_type(8))) short bf16x8;
typedef __attribute__((ext_vector_type(8))) unsigned short u16x8;
typedef __attribute__((ext_vector_type(4))) float f32x4;

__device__ __forceinline__ unsigned short f2bf(float f) {
  union { float f; unsigned u; } v; v.f = f;
  unsigned r = v.u + 0x7FFFu + ((v.u >> 16) & 1u);
  return (unsigned short)(r >> 16);
}
__device__ __forceinline__ float bf2f(unsigned short s) {
  union { unsigned u; float f; } v; v.u = ((unsigned)s) << 16;
  return v.f;
}

// Problem constants
// B=64 T=512 E=300 V=50000 H=2048 WP=2 OUT=5
// padded: EP=320, TP=516, KP=1600, M=B*T=32768

// ---------- kernel 1: W1 -> W1bT bf16 [2048][1600] (transposed, K-padded) ----------
__global__ __launch_bounds__(256) void prepw1_kernel(
    const float* __restrict__ W1, unsigned short* __restrict__ W1bT) {
  __shared__ float tile[64][65];
  int kb = blockIdx.x % 25;   // K tile (padded K = 1600 = 25*64)
  int hb = blockIdx.x / 25;   // H tile (2048 = 32*64)
  int win = kb / 5;
  int e0 = (kb % 5) << 6;
  int hh = threadIdx.x & 63;
  int kq = threadIdx.x >> 6;
#pragma unroll
  for (int kk = kq; kk < 64; kk += 4) {
    int e = e0 + kk;
    float v = 0.f;
    if (e < 300) v = W1[(size_t)(win * 300 + e) * 2048 + hb * 64 + hh];
    tile[kk][hh] = v;
  }
  __syncthreads();
  int kk = threadIdx.x & 63;
  int hq = threadIdx.x >> 6;
#pragma unroll
  for (int h = hq; h < 64; h += 4) {
    W1bT[(size_t)(hb * 64 + h) * 1600 + kb * 64 + kk] = f2bf(tile[kk][h]);
  }
}

// ---------- kernel 2: gather embeddings -> P bf16 [64][516][320] ----------
__global__ __launch_bounds__(320) void gather_kernel(
    const int* __restrict__ idxs, const float* __restrict__ emb,
    unsigned short* __restrict__ P) {
  int g = blockIdx.x;   // b*516 + tp
  int b = g / 516;
  int tp = g - b * 516;
  int tok = 0;
  if (tp >= 2 && tp < 514) tok = idxs[b * 512 + tp - 2];
  int e = threadIdx.x;
  float v = (e < 300) ? emb[(size_t)tok * 300 + e] : 0.f;
  P[(size_t)g * 320 + e] = f2bf(v);
}

// ---------- kernel 3: GEMM  Z[b*512+t][h] = sum_k A * W1bT + b1[h]  (bf16, f32 acc) ----------
__global__ __launch_bounds__(256) void gemm_kernel(
    const unsigned short* __restrict__ P,
    const unsigned short* __restrict__ W1bT,
    const float* __restrict__ b1,
    unsigned short* __restrict__ Z) {
  __shared__ unsigned short As[128 * 64];  // [row][k] 16KB
  __shared__ unsigned short Bs[128 * 64];  // [col][k] 16KB
  const int tid = threadIdx.x;
  const int lane = tid & 63;
  const int w = tid >> 6;
  const int wm = w >> 1, wn = w & 1;
  const int lr = lane & 15;
  const int lk = (lane >> 4) << 3;

  const int nt = blockIdx.x & 15;   // 2048/128
  const int mt = blockIdx.x >> 4;   // 32768/128
  const int b = mt >> 2;            // 4 tiles per batch
  const int t0 = (mt & 3) << 7;

  f32x4 acc[4][4];
#pragma unroll
  for (int i = 0; i < 4; i++)
#pragma unroll
    for (int j = 0; j < 4; j++) acc[i][j] = (f32x4){0.f, 0.f, 0.f, 0.f};

  for (int kt = 0; kt < 25; ++kt) {
    const int win = kt / 5;
    const int e0 = (kt % 5) << 6;
#pragma unroll
    for (int j = 0; j < 4; ++j) {
      int chunk = tid + j * 256;
      int row = chunk >> 3, kb = chunk & 7;
      const unsigned short* src =
          P + (size_t)(b * 516 + t0 + row + win) * 320 + e0 + (kb << 3);
      __builtin_amdgcn_global_load_lds(
          (const __attribute__((address_space(1))) unsigned int*)src,
          (__attribute__((address_space(3))) unsigned int*)&As[chunk << 3],
          16, 0, 0);
    }
#pragma unroll
    for (int j = 0; j < 4; ++j) {
      int chunk = tid + j * 256;
      int col = chunk >> 3, kb = chunk & 7;
      const unsigned short* src =
          W1bT + (size_t)(nt * 128 + col) * 1600 + (kt << 6) + (kb << 3);
      __builtin_amdgcn_global_load_lds(
          (const __attribute__((address_space(1))) unsigned int*)src,
          (__attribute__((address_space(3))) unsigned int*)&Bs[chunk << 3],
          16, 0, 0);
    }
    __syncthreads();
#pragma unroll
    for (int ks = 0; ks < 64; ks += 32) {
      bf16x8 af[4], bv[4];
#pragma unroll
      for (int am = 0; am < 4; ++am)
        af[am] = *(const bf16x8*)&As[((wm << 6) + (am << 4) + lr) * 64 + ks + lk];
#pragma unroll
      for (int bn = 0; bn < 4; ++bn)
        bv[bn] = *(const bf16x8*)&Bs[((wn << 6) + (bn << 4) + lr) * 64 + ks + lk];
#pragma unroll
      for (int am = 0; am < 4; ++am)
#pragma unroll
        for (int bn = 0; bn < 4; ++bn)
          acc[am][bn] = __builtin_amdgcn_mfma_f32_16x16x32_bf16(
              af[am], bv[bn], acc[am][bn], 0, 0, 0);
    }
    __syncthreads();
  }

  const int rbase = mt * 128 + (wm << 6) + ((lane >> 4) << 2);
  const int cbase = nt * 128 + (wn << 6) + lr;
  float b1v[4];
#pragma unroll
  for (int bn = 0; bn < 4; ++bn) b1v[bn] = b1[cbase + (bn << 4)];
#pragma unroll
  for (int am = 0; am < 4; ++am)
#pragma unroll
    for (int bn = 0; bn < 4; ++bn)
#pragma unroll
      for (int j = 0; j < 4; ++j) {
        int r = rbase + (am << 4) + j;
        int c = cbase + (bn << 4);
        Z[(size_t)r * 2048 + c] = f2bf(acc[am][bn][j] + b1v[bn]);
      }
}

// ---------- kernel 4: sequential scan, one block (4 waves) per batch ----------
// thread tid owns h = tid*8 .. tid*8+7.  prev state lives in registers
// (identical across all threads; softmax recomputed redundantly per thread).
__global__ __launch_bounds__(256, 1) void scan_kernel(
    const unsigned short* __restrict__ Z, const float* __restrict__ W1,
    const float* __restrict__ W2, const float* __restrict__ b2,
    const float* __restrict__ istate, float* __restrict__ out) {
  const int b = blockIdx.x;
  const int tid = threadIdx.x;
  const int lane = tid & 63;
  const int wv = tid >> 6;
  const unsigned short* Zb = Z + (size_t)b * 512 * 2048;
  float* outb = out + (size_t)b * 512 * 5;

  // per-thread weight registers
  float w1p[8][10];
#pragma unroll
  for (int i = 0; i < 10; ++i) {
    const float4* r4 =
        (const float4*)&W1[(size_t)(1500 + i) * 2048 + tid * 8];
    float4 a = r4[0], c = r4[1];
    w1p[0][i] = a.x; w1p[1][i] = a.y; w1p[2][i] = a.z; w1p[3][i] = a.w;
    w1p[4][i] = c.x; w1p[5][i] = c.y; w1p[6][i] = c.z; w1p[7][i] = c.w;
  }
  float w2r[8][5];
#pragma unroll
  for (int j = 0; j < 8; ++j)
#pragma unroll
    for (int k = 0; k < 5; ++k) w2r[j][k] = W2[(tid * 8 + j) * 5 + k];
  const float b20 = b2[0], b21 = b2[1], b22 = b2[2], b23 = b2[3],
              b24 = b2[4];

  // recurrent state in registers (uniform across threads)
  float p0 = istate[0], p1 = istate[1], p2 = istate[2], p3 = istate[3],
        p4 = istate[4], p5 = istate[5], p6 = istate[6], p7 = istate[7],
        p8 = istate[8], p9 = istate[9];

  __shared__ float part[2][4][8];  // [parity][wave][k(padded to 8 for align)]

  u16x8 zc = *(const u16x8*)&Zb[tid * 8];

  for (int t = 0; t < 512; ++t) {
    // ---- stage A: per-thread partial y over its 8 h-units ----
    float y0 = 0.f, y1 = 0.f, y2 = 0.f, y3 = 0.f, y4 = 0.f;
#pragma unroll
    for (int j = 0; j < 8; ++j) {
      float x = bf2f(zc[j]);  // z already contains b1
      x = fmaf(p0, w1p[j][0], x);
      x = fmaf(p1, w1p[j][1], x);
      x = fmaf(p2, w1p[j][2], x);
      x = fmaf(p3, w1p[j][3], x);
      x = fmaf(p4, w1p[j][4], x);
      x = fmaf(p5, w1p[j][5], x);
      x = fmaf(p6, w1p[j][6], x);
      x = fmaf(p7, w1p[j][7], x);
      x = fmaf(p8, w1p[j][8], x);
      x = fmaf(p9, w1p[j][9], x);
      x = fmaxf(x, 0.f);
      y0 = fmaf(x, w2r[j][0], y0);
      y1 = fmaf(x, w2r[j][1], y1);
      y2 = fmaf(x, w2r[j][2], y2);
      y3 = fmaf(x, w2r[j][3], y3);
      y4 = fmaf(x, w2r[j][4], y4);
    }
    // prefetch next Z row (latency hides under the reduction)
    if (t + 1 < 512) zc = *(const u16x8*)&Zb[(size_t)(t + 1) * 2048 + tid * 8];

    // ---- intra-wave butterfly reduce (5 independent chains) ----
#pragma unroll
    for (int off = 1; off < 64; off <<= 1) {
      y0 += __shfl_xor(y0, off, 64);
      y1 += __shfl_xor(y1, off, 64);
      y2 += __shfl_xor(y2, off, 64);
      y3 += __shfl_xor(y3, off, 64);
      y4 += __shfl_xor(y4, off, 64);
    }
    const int pp = t & 1;
    if (lane == 0) {
      *(float4*)&part[pp][wv][0] = (float4){y0, y1, y2, y3};
      part[pp][wv][4] = y4;
    }
    __syncthreads();

    // ---- stage B: redundant final reduce + softmax on every thread ----
    float s0 = b20 + ((part[pp][0][0] + part[pp][1][0]) +
                      (part[pp][2][0] + part[pp][3][0]));
    float s1 = b21 + ((part[pp][0][1] + part[pp][1][1]) +
                      (part[pp][2][1] + part[pp][3][1]));
    float s2 = b22 + ((part[pp][0][2] + part[pp][1][2]) +
                      (part[pp][2][2] + part[pp][3][2]));
    float s3 = b23 + ((part[pp][0][3] + part[pp][1][3]) +
                      (part[pp][2][3] + part[pp][3][3]));
    float s4 = b24 + ((part[pp][0][4] + part[pp][1][4]) +
                      (part[pp][2][4] + part[pp][3][4]));

    if (tid < 5) {  // coalesced 20B store of the 5 logits
      float v = s0;
      v = (tid == 1) ? s1 : v;
      v = (tid == 2) ? s2 : v;
      v = (tid == 3) ? s3 : v;
      v = (tid == 4) ? s4 : v;
      outb[t * 5 + tid] = v;
    }

    float m = fmaxf(fmaxf(fmaxf(s0, s1), fmaxf(s2, s3)), s4);
    float e0 = __expf(s0 - m), e1 = __expf(s1 - m), e2 = __expf(s2 - m),
          e3 = __expf(s3 - m), e4 = __expf(s4 - m);
    float d = ((e0 + e1) + (e2 + e3)) + e4;
    float rd = __builtin_amdgcn_rcpf(d);
    p0 = p5; p1 = p6; p2 = p7; p3 = p8; p4 = p9;
    p5 = e0 * rd; p6 = e1 * rd; p7 = e2 * rd; p8 = e3 * rd; p9 = e4 * rd;
    // no second barrier: next step writes part[pp^1]; the step-(t+1) barrier
    // orders those writes against this step's reads of part[pp].
  }
}

// ---------- launcher ----------
extern "C" void kernel_launch(void* const* d_in, const int* in_sizes, int n_in,
                              void* d_out, int out_size, void* d_ws,
                              size_t ws_size, hipStream_t stream) {
  const int* idxs = (const int*)d_in[0];
  const float* emb = (const float*)d_in[1];
  const float* W1 = (const float*)d_in[2];
  const float* b1 = (const float*)d_in[3];
  const float* W2 = (const float*)d_in[4];
  const float* b2 = (const float*)d_in[5];
  const float* istate = (const float*)d_in[6];
  float* out = (float*)d_out;

  char* ws = (char*)d_ws;
  unsigned short* P = (unsigned short*)ws;                          // 21,135,360 B
  unsigned short* W1bT = (unsigned short*)(ws + 21135360);          // 6,553,600 B
  unsigned short* Z = (unsigned short*)(ws + 21135360 + 6553600);   // 134,217,728 B

  hipLaunchKernelGGL(prepw1_kernel, dim3(25 * 32), dim3(256), 0, stream, W1, W1bT);
  hipLaunchKernelGGL(gather_kernel, dim3(64 * 516), dim3(320), 0, stream, idxs, emb, P);
  hipLaunchKernelGGL(gemm_kernel, dim3(256 * 16), dim3(256), 0, stream, P, W1bT, b1, Z);
  hipLaunchKernelGGL(scan_kernel, dim3(64), dim3(256), 0, stream, Z, W1, W2, b2,
                     istate, out);
}

// Round 6
// 660.650 us; speedup vs baseline: 1.9164x; 1.2394x over previous
//
#include <hip/hip_runtime.h>

// ---------- types ----------
typedef __attribute__((ext_vector_type(8))) short bf16x8;
typedef __attribute__((ext_vector_type(8))) unsigned short u16x8;
typedef __attribute__((ext_vector_type(4))) float f32x4;

__device__ __forceinline__ unsigned short f2bf(float f) {
  union { float f; unsigned u; } v; v.f = f;
  unsigned r = v.u + 0x7FFFu + ((v.u >> 16) & 1u);
  return (unsigned short)(r >> 16);
}
__device__ __forceinline__ float bf2f(unsigned short s) {
  union { unsigned u; float f; } v; v.u = ((unsigned)s) << 16;
  return v.f;
}

// DPP-based wave64 sum; result valid in lane 63 only.
template <int CTRL>
__device__ __forceinline__ float dpp_add(float v) {
  int m = __builtin_amdgcn_update_dpp(0, __float_as_int(v), CTRL, 0xf, 0xf, true);
  return v + __int_as_float(m);
}
__device__ __forceinline__ float wave_sum63(float v) {
  v = dpp_add<0x111>(v);  // row_shr:1
  v = dpp_add<0x112>(v);  // row_shr:2
  v = dpp_add<0x114>(v);  // row_shr:4
  v = dpp_add<0x118>(v);  // row_shr:8  -> lane15 of each row has row sum
  v = dpp_add<0x142>(v);  // row_bcast:15
  v = dpp_add<0x143>(v);  // row_bcast:31 -> lane63 has wave sum
  return v;
}

// Problem constants
// B=64 T=512 E=300 V=50000 H=2048 WP=2 OUT=5
// padded: EP=320, TP=516, KP=1600, M=B*T=32768

// ---------- kernel 1: W1 -> W1bT bf16 [2048][1600] (transposed, K-padded) ----------
__global__ __launch_bounds__(256) void prepw1_kernel(
    const float* __restrict__ W1, unsigned short* __restrict__ W1bT) {
  __shared__ float tile[64][65];
  int kb = blockIdx.x % 25;   // K tile (padded K = 1600 = 25*64)
  int hb = blockIdx.x / 25;   // H tile (2048 = 32*64)
  int win = kb / 5;
  int e0 = (kb % 5) << 6;
  int hh = threadIdx.x & 63;
  int kq = threadIdx.x >> 6;
#pragma unroll
  for (int kk = kq; kk < 64; kk += 4) {
    int e = e0 + kk;
    float v = 0.f;
    if (e < 300) v = W1[(size_t)(win * 300 + e) * 2048 + hb * 64 + hh];
    tile[kk][hh] = v;
  }
  __syncthreads();
  int kk = threadIdx.x & 63;
  int hq = threadIdx.x >> 6;
#pragma unroll
  for (int h = hq; h < 64; h += 4) {
    W1bT[(size_t)(hb * 64 + h) * 1600 + kb * 64 + kk] = f2bf(tile[kk][h]);
  }
}

// ---------- kernel 2: gather embeddings -> P bf16 [64][516][320] ----------
__global__ __launch_bounds__(320) void gather_kernel(
    const int* __restrict__ idxs, const float* __restrict__ emb,
    unsigned short* __restrict__ P) {
  int g = blockIdx.x;   // b*516 + tp
  int b = g / 516;
  int tp = g - b * 516;
  int tok = 0;
  if (tp >= 2 && tp < 514) tok = idxs[b * 512 + tp - 2];
  int e = threadIdx.x;
  float v = (e < 300) ? emb[(size_t)tok * 300 + e] : 0.f;
  P[(size_t)g * 320 + e] = f2bf(v);
}

// ---------- kernel 3: GEMM  Z[b*512+t][h] = sum_k A * W1bT + b1[h]  (bf16, f32 acc) ----------
__global__ __launch_bounds__(256) void gemm_kernel(
    const unsigned short* __restrict__ P,
    const unsigned short* __restrict__ W1bT,
    const float* __restrict__ b1,
    unsigned short* __restrict__ Z) {
  __shared__ unsigned short As[128 * 64];  // [row][k] 16KB
  __shared__ unsigned short Bs[128 * 64];  // [col][k] 16KB
  const int tid = threadIdx.x;
  const int lane = tid & 63;
  const int w = tid >> 6;
  const int wm = w >> 1, wn = w & 1;
  const int lr = lane & 15;
  const int lk = (lane >> 4) << 3;

  const int nt = blockIdx.x & 15;   // 2048/128
  const int mt = blockIdx.x >> 4;   // 32768/128
  const int b = mt >> 2;            // 4 tiles per batch
  const int t0 = (mt & 3) << 7;

  f32x4 acc[4][4];
#pragma unroll
  for (int i = 0; i < 4; i++)
#pragma unroll
    for (int j = 0; j < 4; j++) acc[i][j] = (f32x4){0.f, 0.f, 0.f, 0.f};

  for (int kt = 0; kt < 25; ++kt) {
    const int win = kt / 5;
    const int e0 = (kt % 5) << 6;
#pragma unroll
    for (int j = 0; j < 4; ++j) {
      int chunk = tid + j * 256;
      int row = chunk >> 3, kb = chunk & 7;
      const unsigned short* src =
          P + (size_t)(b * 516 + t0 + row + win) * 320 + e0 + (kb << 3);
      __builtin_amdgcn_global_load_lds(
          (const __attribute__((address_space(1))) unsigned int*)src,
          (__attribute__((address_space(3))) unsigned int*)&As[chunk << 3],
          16, 0, 0);
    }
#pragma unroll
    for (int j = 0; j < 4; ++j) {
      int chunk = tid + j * 256;
      int col = chunk >> 3, kb = chunk & 7;
      const unsigned short* src =
          W1bT + (size_t)(nt * 128 + col) * 1600 + (kt << 6) + (kb << 3);
      __builtin_amdgcn_global_load_lds(
          (const __attribute__((address_space(1))) unsigned int*)src,
          (__attribute__((address_space(3))) unsigned int*)&Bs[chunk << 3],
          16, 0, 0);
    }
    __syncthreads();
#pragma unroll
    for (int ks = 0; ks < 64; ks += 32) {
      bf16x8 af[4], bv[4];
#pragma unroll
      for (int am = 0; am < 4; ++am)
        af[am] = *(const bf16x8*)&As[((wm << 6) + (am << 4) + lr) * 64 + ks + lk];
#pragma unroll
      for (int bn = 0; bn < 4; ++bn)
        bv[bn] = *(const bf16x8*)&Bs[((wn << 6) + (bn << 4) + lr) * 64 + ks + lk];
#pragma unroll
      for (int am = 0; am < 4; ++am)
#pragma unroll
        for (int bn = 0; bn < 4; ++bn)
          acc[am][bn] = __builtin_amdgcn_mfma_f32_16x16x32_bf16(
              af[am], bv[bn], acc[am][bn], 0, 0, 0);
    }
    __syncthreads();
  }

  const int rbase = mt * 128 + (wm << 6) + ((lane >> 4) << 2);
  const int cbase = nt * 128 + (wn << 6) + lr;
  float b1v[4];
#pragma unroll
  for (int bn = 0; bn < 4; ++bn) b1v[bn] = b1[cbase + (bn << 4)];
#pragma unroll
  for (int am = 0; am < 4; ++am)
#pragma unroll
    for (int bn = 0; bn < 4; ++bn)
#pragma unroll
      for (int j = 0; j < 4; ++j) {
        int r = rbase + (am << 4) + j;
        int c = cbase + (bn << 4);
        Z[(size_t)r * 2048 + c] = f2bf(acc[am][bn][j] + b1v[bn]);
      }
}

// ---------- kernel 4: sequential scan, one block (4 waves) per batch ----------
// thread tid owns h = tid*8 .. tid*8+7.  prev state lives in registers
// (identical across all threads; softmax recomputed redundantly per thread).
__global__ __launch_bounds__(256, 1) void scan_kernel(
    const unsigned short* __restrict__ Z, const float* __restrict__ W1,
    const float* __restrict__ W2, const float* __restrict__ b2,
    const float* __restrict__ istate, float* __restrict__ out) {
  const int b = blockIdx.x;
  const int tid = threadIdx.x;
  const int lane = tid & 63;
  const int wv = tid >> 6;
  const unsigned short* Zb = Z + (size_t)b * 512 * 2048;
  float* outb = out + (size_t)b * 512 * 5;

  // per-thread weight registers
  float w1p[8][10];
#pragma unroll
  for (int i = 0; i < 10; ++i) {
    const float4* r4 =
        (const float4*)&W1[(size_t)(1500 + i) * 2048 + tid * 8];
    float4 a = r4[0], c = r4[1];
    w1p[0][i] = a.x; w1p[1][i] = a.y; w1p[2][i] = a.z; w1p[3][i] = a.w;
    w1p[4][i] = c.x; w1p[5][i] = c.y; w1p[6][i] = c.z; w1p[7][i] = c.w;
  }
  float w2r[8][5];
#pragma unroll
  for (int j = 0; j < 8; ++j)
#pragma unroll
    for (int k = 0; k < 5; ++k) w2r[j][k] = W2[(tid * 8 + j) * 5 + k];
  const float b20 = b2[0], b21 = b2[1], b22 = b2[2], b23 = b2[3],
              b24 = b2[4];

  // recurrent state in registers (uniform across threads)
  float p0 = istate[0], p1 = istate[1], p2 = istate[2], p3 = istate[3],
        p4 = istate[4], p5 = istate[5], p6 = istate[6], p7 = istate[7],
        p8 = istate[8], p9 = istate[9];

  __shared__ float part[2][4][8];  // [parity][wave][k(padded to 8)]

  // software pipeline: prefetch distance 2 on the Z row
  u16x8 zc = *(const u16x8*)&Zb[tid * 8];
  u16x8 zn = *(const u16x8*)&Zb[(size_t)2048 + tid * 8];

  for (int t = 0; t < 512; ++t) {
    // ---- stage A: per-thread partial y over its 8 h-units ----
    float y0 = 0.f, y1 = 0.f, y2 = 0.f, y3 = 0.f, y4 = 0.f;
#pragma unroll
    for (int j = 0; j < 8; ++j) {
      float x = bf2f(zc[j]);  // z already contains b1
      x = fmaf(p0, w1p[j][0], x);
      x = fmaf(p1, w1p[j][1], x);
      x = fmaf(p2, w1p[j][2], x);
      x = fmaf(p3, w1p[j][3], x);
      x = fmaf(p4, w1p[j][4], x);
      x = fmaf(p5, w1p[j][5], x);
      x = fmaf(p6, w1p[j][6], x);
      x = fmaf(p7, w1p[j][7], x);
      x = fmaf(p8, w1p[j][8], x);
      x = fmaf(p9, w1p[j][9], x);
      x = fmaxf(x, 0.f);
      y0 = fmaf(x, w2r[j][0], y0);
      y1 = fmaf(x, w2r[j][1], y1);
      y2 = fmaf(x, w2r[j][2], y2);
      y3 = fmaf(x, w2r[j][3], y3);
      y4 = fmaf(x, w2r[j][4], y4);
    }
    // issue prefetch for t+2 (clamped; covers L3/HBM latency across 2 steps)
    int tn = (t + 2 < 512) ? (t + 2) : 511;
    u16x8 zf = *(const u16x8*)&Zb[(size_t)tn * 2048 + tid * 8];

    // ---- intra-wave reduce on the VALU pipe (DPP), sum lands in lane 63 ----
    y0 = wave_sum63(y0);
    y1 = wave_sum63(y1);
    y2 = wave_sum63(y2);
    y3 = wave_sum63(y3);
    y4 = wave_sum63(y4);
    const int pp = t & 1;
    if (lane == 63) {
      *(float4*)&part[pp][wv][0] = (float4){y0, y1, y2, y3};
      part[pp][wv][4] = y4;
    }
    __syncthreads();

    // ---- stage B: redundant final reduce + softmax on every thread ----
    float4 q0 = *(const float4*)&part[pp][0][0];
    float4 q1 = *(const float4*)&part[pp][1][0];
    float4 q2 = *(const float4*)&part[pp][2][0];
    float4 q3 = *(const float4*)&part[pp][3][0];
    float s0 = b20 + ((q0.x + q1.x) + (q2.x + q3.x));
    float s1 = b21 + ((q0.y + q1.y) + (q2.y + q3.y));
    float s2 = b22 + ((q0.z + q1.z) + (q2.z + q3.z));
    float s3 = b23 + ((q0.w + q1.w) + (q2.w + q3.w));
    float s4 = b24 + ((part[pp][0][4] + part[pp][1][4]) +
                      (part[pp][2][4] + part[pp][3][4]));

    if (tid < 5) {  // 20B store of the 5 logits
      float v = s0;
      v = (tid == 1) ? s1 : v;
      v = (tid == 2) ? s2 : v;
      v = (tid == 3) ? s3 : v;
      v = (tid == 4) ? s4 : v;
      outb[t * 5 + tid] = v;
    }

    float m = fmaxf(fmaxf(fmaxf(s0, s1), fmaxf(s2, s3)), s4);
    float e0 = __expf(s0 - m), e1 = __expf(s1 - m), e2 = __expf(s2 - m),
          e3 = __expf(s3 - m), e4 = __expf(s4 - m);
    float d = ((e0 + e1) + (e2 + e3)) + e4;
    float rd = __builtin_amdgcn_rcpf(d);
    p0 = p5; p1 = p6; p2 = p7; p3 = p8; p4 = p9;
    p5 = e0 * rd; p6 = e1 * rd; p7 = e2 * rd; p8 = e3 * rd; p9 = e4 * rd;

    zc = zn; zn = zf;
    // no second barrier: next step writes part[pp^1]; the step-(t+1) barrier
    // orders those writes against this step's reads of part[pp].
  }
}

// ---------- launcher ----------
extern "C" void kernel_launch(void* const* d_in, const int* in_sizes, int n_in,
                              void* d_out, int out_size, void* d_ws,
                              size_t ws_size, hipStream_t stream) {
  const int* idxs = (const int*)d_in[0];
  const float* emb = (const float*)d_in[1];
  const float* W1 = (const float*)d_in[2];
  const float* b1 = (const float*)d_in[3];
  const float* W2 = (const float*)d_in[4];
  const float* b2 = (const float*)d_in[5];
  const float* istate = (const float*)d_in[6];
  float* out = (float*)d_out;

  char* ws = (char*)d_ws;
  unsigned short* P = (unsigned short*)ws;                          // 21,135,360 B
  unsigned short* W1bT = (unsigned short*)(ws + 21135360);          // 6,553,600 B
  unsigned short* Z = (unsigned short*)(ws + 21135360 + 6553600);   // 134,217,728 B

  hipLaunchKernelGGL(prepw1_kernel, dim3(25 * 32), dim3(256), 0, stream, W1, W1bT);
  hipLaunchKernelGGL(gather_kernel, dim3(64 * 516), dim3(320), 0, stream, idxs, emb, P);
  hipLaunchKernelGGL(gemm_kernel, dim3(256 * 16), dim3(256), 0, stream, P, W1bT, b1, Z);
  hipLaunchKernelGGL(scan_kernel, dim3(64), dim3(256), 0, stream, Z, W1, W2, b2,
                     istate, out);
}